// Round 1
// baseline (131.246 us; speedup 1.0000x reference)
//
#include <hip/hip_runtime.h>
#include <hip/hip_bf16.h>
#include <stdint.h>

#define E_ 8
#define H_ 1024
#define I_ 1024
#define T_ 8192
#define BM 128
#define BK 32

typedef __attribute__((ext_vector_type(4))) float f32x4;
typedef __attribute__((ext_vector_type(8))) short bf16x8;

__device__ __forceinline__ unsigned short f2bf(float f) {
  union { float f; unsigned int u; } v; v.f = f;
  unsigned int lsb = (v.u >> 16) & 1u;
  v.u += 0x7fffu + lsb;          // round-to-nearest-even
  return (unsigned short)(v.u >> 16);
}

__device__ __forceinline__ void gload_lds16(const void* g, void* l) {
  __builtin_amdgcn_global_load_lds(
      (const __attribute__((address_space(1))) unsigned int*)g,
      (__attribute__((address_space(3))) unsigned int*)l,
      16, 0, 0);
}

// ---------------- conversion: f32 -> bf16, vectorized ----------------
__global__ void convert_f32_bf16(const float* __restrict__ in,
                                 unsigned short* __restrict__ out, int n) {
  int i = (blockIdx.x * blockDim.x + threadIdx.x) * 4;
  if (i >= n) return;
  float4 v = *reinterpret_cast<const float4*>(in + i);
  ushort4 o;
  o.x = f2bf(v.x); o.y = f2bf(v.y); o.z = f2bf(v.z); o.w = f2bf(v.w);
  *reinterpret_cast<ushort4*>(out + i) = o;
}

// ------------- transpose+convert: [E][R][C] f32 -> [E][C][R] bf16 -------------
__global__ void transpose_f32_to_bf16(const float* __restrict__ in,
                                      unsigned short* __restrict__ out,
                                      int R, int C) {
  __shared__ float tile[32][33];
  int e = blockIdx.z;
  const float* inp = in + (size_t)e * R * C;
  unsigned short* outp = out + (size_t)e * R * C;
  int c0 = blockIdx.x * 32, r0 = blockIdx.y * 32;
  for (int rr = threadIdx.y; rr < 32; rr += 8)
    tile[rr][threadIdx.x] = inp[(size_t)(r0 + rr) * C + c0 + threadIdx.x];
  __syncthreads();
  for (int rr = threadIdx.y; rr < 32; rr += 8)
    outp[(size_t)(c0 + rr) * R + r0 + threadIdx.x] = f2bf(tile[threadIdx.x][rr]);
}

// ------------- expert lookup from device-side counts -------------
__device__ __forceinline__ bool find_tile(const int* counts, int ty,
                                          int& row_start, int& rows) {
  int tacc = 0, off = 0;
  int expert = -1;
  #pragma unroll
  for (int e = 0; e < E_; ++e) {
    int c = counts[e];
    int te = (c + BM - 1) >> 7;
    if (expert < 0 && ty < tacc + te) {
      expert = e;
      int lt = ty - tacc;
      row_start = off + lt * BM;
      rows = min(BM, c - lt * BM);
    }
    tacc += te; off += c;
  }
  if (expert < 0) return false;
  row_start |= (expert << 24);  // pack expert in high bits (row_start < 2^24)
  return true;
}

// ---------------- GEMM1 + SwiGLU ----------------
// X [T][H] bf16, W1T [E][2I][H] bf16 -> H [T][I] bf16
// block: 256 thr (4 waves, each 32 rows x 128 local-n), grid (I/64, tiles)
// local n 0..63 = gate cols bn*64+ln ; 64..127 = up cols I + bn*64 + (ln-64)
__launch_bounds__(256, 2)
__global__ void gemm1_swiglu(const unsigned short* __restrict__ X,
                             const unsigned short* __restrict__ W1T,
                             const int* __restrict__ counts,
                             unsigned short* __restrict__ Hout) {
  __shared__ unsigned short As[BM * BK];
  __shared__ unsigned short Bs[BM * BK];
  int row_start = 0, rows = 0;
  if (!find_tile(counts, blockIdx.y, row_start, rows)) return;
  int expert = row_start >> 24; row_start &= 0xFFFFFF;
  int bn = blockIdx.x;  // 0..15
  int tid = threadIdx.x, wid = tid >> 6, lane = tid & 63;
  const unsigned short* Wp = W1T + (size_t)expert * (2 * I_) * H_;

  f32x4 acc[2][8];
  #pragma unroll
  for (int m = 0; m < 2; ++m)
    #pragma unroll
    for (int n = 0; n < 8; ++n) acc[m][n] = {0.f, 0.f, 0.f, 0.f};

  int l4 = lane >> 2;          // 0..15 : row within 16-row chunk
  int kof = (lane & 3) * 8;    // k element offset of this lane's 16B
  int lr = lane & 15, lk = (lane >> 4) * 8;

  for (int kt = 0; kt < H_ / BK; ++kt) {
    #pragma unroll
    for (int i = 0; i < 2; ++i) {
      int rl = wid * 32 + i * 16 + l4;
      int gr = row_start + min(rl, rows - 1);
      gload_lds16(X + (size_t)gr * H_ + kt * BK + kof, &As[(wid * 32 + i * 16) * BK]);
    }
    #pragma unroll
    for (int i = 0; i < 2; ++i) {
      int ln = wid * 32 + i * 16 + l4;
      int gn = bn * 64 + ln + ((ln >= 64) ? (I_ - 64) : 0);
      gload_lds16(Wp + (size_t)gn * H_ + kt * BK + kof, &Bs[(wid * 32 + i * 16) * BK]);
    }
    __syncthreads();
    bf16x8 a[2], b[8];
    #pragma unroll
    for (int m = 0; m < 2; ++m)
      a[m] = *reinterpret_cast<const bf16x8*>(&As[(wid * 32 + m * 16 + lr) * BK + lk]);
    #pragma unroll
    for (int n = 0; n < 8; ++n)
      b[n] = *reinterpret_cast<const bf16x8*>(&Bs[(n * 16 + lr) * BK + lk]);
    #pragma unroll
    for (int m = 0; m < 2; ++m)
      #pragma unroll
      for (int n = 0; n < 8; ++n)
        acc[m][n] = __builtin_amdgcn_mfma_f32_16x16x32_bf16(a[m], b[n], acc[m][n], 0, 0, 0);
    __syncthreads();
  }

  int lq = lane >> 4;
  #pragma unroll
  for (int m = 0; m < 2; ++m)
    #pragma unroll
    for (int n = 0; n < 4; ++n) {
      f32x4 g = acc[m][n], u = acc[m][n + 4];
      #pragma unroll
      for (int r = 0; r < 4; ++r) {
        int rl = wid * 32 + m * 16 + lq * 4 + r;
        if (rl < rows) {
          float gv = g[r];
          float hv = (gv / (1.f + __expf(-gv))) * u[r];
          Hout[(size_t)(row_start + rl) * I_ + bn * 64 + n * 16 + lr] = f2bf(hv);
        }
      }
    }
}

// ---------------- GEMM2 ----------------
// Hin [T][I] bf16, W2T [E][H][I] bf16 -> Out [T][H] f32
// block: 256 thr (4 waves 2x2, each 64x64), grid (H/128, tiles)
__launch_bounds__(256, 2)
__global__ void gemm2(const unsigned short* __restrict__ Hin,
                      const unsigned short* __restrict__ W2T,
                      const int* __restrict__ counts,
                      float* __restrict__ Out) {
  __shared__ unsigned short As[BM * BK];
  __shared__ unsigned short Bs[BM * BK];
  int row_start = 0, rows = 0;
  if (!find_tile(counts, blockIdx.y, row_start, rows)) return;
  int expert = row_start >> 24; row_start &= 0xFFFFFF;
  int bn = blockIdx.x;  // 0..7
  int tid = threadIdx.x, wid = tid >> 6, lane = tid & 63;
  int wr = wid >> 1, wc = wid & 1;
  const unsigned short* Wp = W2T + (size_t)expert * H_ * I_;

  f32x4 acc[4][4];
  #pragma unroll
  for (int m = 0; m < 4; ++m)
    #pragma unroll
    for (int n = 0; n < 4; ++n) acc[m][n] = {0.f, 0.f, 0.f, 0.f};

  int l4 = lane >> 2;
  int kof = (lane & 3) * 8;
  int lr = lane & 15, lk = (lane >> 4) * 8;

  for (int kt = 0; kt < I_ / BK; ++kt) {
    #pragma unroll
    for (int i = 0; i < 2; ++i) {
      int rl = wid * 32 + i * 16 + l4;
      int gr = row_start + min(rl, rows - 1);
      gload_lds16(Hin + (size_t)gr * I_ + kt * BK + kof, &As[(wid * 32 + i * 16) * BK]);
    }
    #pragma unroll
    for (int i = 0; i < 2; ++i) {
      int ln = wid * 32 + i * 16 + l4;
      int gn = bn * 128 + ln;
      gload_lds16(Wp + (size_t)gn * I_ + kt * BK + kof, &Bs[(wid * 32 + i * 16) * BK]);
    }
    __syncthreads();
    bf16x8 a[4], b[4];
    #pragma unroll
    for (int m = 0; m < 4; ++m)
      a[m] = *reinterpret_cast<const bf16x8*>(&As[(wr * 64 + m * 16 + lr) * BK + lk]);
    #pragma unroll
    for (int n = 0; n < 4; ++n)
      b[n] = *reinterpret_cast<const bf16x8*>(&Bs[(wc * 64 + n * 16 + lr) * BK + lk]);
    #pragma unroll
    for (int m = 0; m < 4; ++m)
      #pragma unroll
      for (int n = 0; n < 4; ++n)
        acc[m][n] = __builtin_amdgcn_mfma_f32_16x16x32_bf16(a[m], b[n], acc[m][n], 0, 0, 0);
    __syncthreads();
  }

  int lq = lane >> 4;
  #pragma unroll
  for (int m = 0; m < 4; ++m)
    #pragma unroll
    for (int n = 0; n < 4; ++n)
      #pragma unroll
      for (int r = 0; r < 4; ++r) {
        int rl = wr * 64 + m * 16 + lq * 4 + r;
        if (rl < rows)
          Out[(size_t)(row_start + rl) * H_ + bn * 128 + wc * 64 + n * 16 + lr] =
              acc[m][n][r];
      }
}

extern "C" void kernel_launch(void* const* d_in, const int* in_sizes, int n_in,
                              void* d_out, int out_size, void* d_ws, size_t ws_size,
                              hipStream_t stream) {
  const float* x  = (const float*)d_in[0];
  const float* w1 = (const float*)d_in[1];   // [E][H][2I]
  const float* w2 = (const float*)d_in[2];   // [E][I][H]
  const int* counts = (const int*)d_in[3];
  float* out = (float*)d_out;

  char* ws = (char*)d_ws;
  unsigned short* xb  = (unsigned short*)ws;                                   // T*H bf16   = 16 MB
  unsigned short* w1t = (unsigned short*)(ws + (size_t)T_ * H_ * 2);           // E*2I*H bf16 = 33.5 MB
  unsigned short* w2t = (unsigned short*)(ws + (size_t)T_ * H_ * 2
                                             + (size_t)E_ * 2 * I_ * H_ * 2);  // E*H*I bf16  = 16.8 MB
  unsigned short* hbuf = (unsigned short*)(ws + (size_t)T_ * H_ * 2
                                              + (size_t)E_ * 2 * I_ * H_ * 2
                                              + (size_t)E_ * H_ * I_ * 2);     // T*I bf16    = 16.8 MB

  // 1) convert x
  convert_f32_bf16<<<(T_ * H_) / 1024, 256, 0, stream>>>(x, xb, T_ * H_);
  // 2) transpose+convert weights
  dim3 tb(32, 8);
  transpose_f32_to_bf16<<<dim3((2 * I_) / 32, H_ / 32, E_), tb, 0, stream>>>(w1, w1t, H_, 2 * I_);
  transpose_f32_to_bf16<<<dim3(H_ / 32, I_ / 32, E_), tb, 0, stream>>>(w2, w2t, I_, H_);
  // 3) grouped GEMM1 + SwiGLU
  int max_tiles = T_ / BM + E_;
  gemm1_swiglu<<<dim3(I_ / 64, max_tiles), 256, 0, stream>>>(xb, w1t, counts, hbuf);
  // 4) grouped GEMM2
  gemm2<<<dim3(H_ / 128, max_tiles), 256, 0, stream>>>(hbuf, w2t, counts, out);
}